// Round 8
// baseline (56.059 us; speedup 1.0000x reference)
//
#include <hip/hip_runtime.h>

typedef float v2f __attribute__((ext_vector_type(2)));

#define D 2
#define DH 5
#define NH 3
#define NW0 (DH*D)            // 10
#define NWS (NH*DH*DH)        // 75
#define NWTOT (NW0+NWS+D*DH)  // 95

#define NPAIR 4               // sample-pairs per thread (8 samples)

// c = 2*log2(e): weights pre-scaled so exp2 needs no argument mul.
#define C_SCALE 2.8853900817779268f
#define K03C 0.10397207708399180f   // 0.3/c
#define K28C 0.97040605462392273f   // 2.8/c
#define LN2  0.69314718055994531f

__device__ __forceinline__ v2f splat(float x){ return (v2f)(x); }
__device__ __forceinline__ v2f vfma(v2f a, v2f b, v2f c){
    return __builtin_elementwise_fma(a, b, c);   // -> v_pk_fma_f32
}

// Packed activation: z' = c*z for a sample-pair;
//   r = 1/(2^{z'}+1);  h = 0.3z+0.7-1.4r;  d' = 0.3/c + (2.8/c)(r-r^2)
__device__ __forceinline__ void act2(v2f zp, v2f& h, v2f& dp) {
    v2f e, r;
    e.x = __builtin_amdgcn_exp2f(zp.x);
    e.y = __builtin_amdgcn_exp2f(zp.y);
    v2f a = e + splat(1.0f);
    r.x = __builtin_amdgcn_rcpf(a.x);
    r.y = __builtin_amdgcn_rcpf(a.y);
    v2f u = vfma(-r, r, r);                      // r - r^2
    dp = vfma(splat(K28C), u, splat(K03C));
    h  = vfma(splat(-1.4f), r, vfma(splat(K03C), zp, splat(0.7f)));
}

// Pre-scale all weights by c into workspace (deterministic, every launch).
__global__ void prescale_kernel(const float* __restrict__ gW0,
                                const float* __restrict__ gWs,
                                const float* __restrict__ gWout,
                                float* __restrict__ wsf) {
    int i = threadIdx.x;
    if (i < NW0)            wsf[i] = C_SCALE * gW0[i];
    else if (i < NW0+NWS)   wsf[i] = C_SCALE * gWs[i - NW0];
    else if (i < NWTOT)     wsf[i] = C_SCALE * gWout[i - NW0 - NWS];
}

__global__ __launch_bounds__(256) void nnflow_kernel(
    const float4* __restrict__ xj4,
    const float* __restrict__ wsf,
    float4* __restrict__ out4,
    int noct)
{
    int t = blockIdx.x * blockDim.x + threadIdx.x;
    if (t >= noct) return;

    // ---- scaled weights: uniform address + const idx -> scalar loads ----
    float w0[DH][D];
    #pragma unroll
    for (int k = 0; k < DH; ++k)
        #pragma unroll
        for (int j = 0; j < D; ++j)
            w0[k][j] = wsf[k * D + j];

    float ws[NH][DH][DH];
    #pragma unroll
    for (int i = 0; i < NH; ++i)
        #pragma unroll
        for (int k = 0; k < DH; ++k)
            #pragma unroll
            for (int j = 0; j < DH; ++j)
                ws[i][k][j] = wsf[NW0 + (i * DH + k) * DH + j];

    float wo[D][DH];
    #pragma unroll
    for (int r = 0; r < D; ++r)
        #pragma unroll
        for (int j = 0; j < DH; ++j)
            wo[r][j] = wsf[NW0 + NWS + r * DH + j];

    // ---- 8 samples = 24 floats = 6 float4, hoisted & coalesced ----
    float4 v[6];
    #pragma unroll
    for (int q = 0; q < 6; ++q)
        v[q] = xj4[(size_t)t * 6 + q];
    const float* f = (const float*)v;

    // pair p = samples (2p, 2p+1): x0 = f[6p], f[6p+3]; x1 = f[6p+1], f[6p+4]; lj = f[6p+2], f[6p+5]
    v2f px0[NPAIR], px1[NPAIR], plj[NPAIR];
    #pragma unroll
    for (int p = 0; p < NPAIR; ++p) {
        px0[p].x = f[6*p + 0]; px0[p].y = f[6*p + 3];
        px1[p].x = f[6*p + 1]; px1[p].y = f[6*p + 4];
        plj[p].x = f[6*p + 2]; plj[p].y = f[6*p + 5];
    }

    v2f ry0[NPAIR], ry1[NPAIR], rld[NPAIR];

    #pragma unroll
    for (int p = 0; p < NPAIR; ++p) {
        v2f x0 = px0[p], x1 = px1[p];

        // ---- layer 0 ----
        v2f h[DH], J0[DH], J1[DH];
        #pragma unroll
        for (int k = 0; k < DH; ++k) {
            v2f z = vfma(splat(w0[k][0]), x0, splat(w0[k][1]) * x1);
            v2f hk, dk;
            act2(z, hk, dk);
            h[k]  = hk;
            J0[k] = splat(w0[k][0]) * dk;
            J1[k] = splat(w0[k][1]) * dk;
        }

        // ---- hidden layers ----
        #pragma unroll
        for (int i = 0; i < NH; ++i) {
            v2f hn[DH], Jn0[DH], Jn1[DH];
            #pragma unroll
            for (int k = 0; k < DH; ++k) {
                v2f z  = splat(ws[i][k][0]) * h[0];
                v2f j0 = splat(ws[i][k][0]) * J0[0];
                v2f j1 = splat(ws[i][k][0]) * J1[0];
                #pragma unroll
                for (int j = 1; j < DH; ++j) {
                    v2f w = splat(ws[i][k][j]);
                    z  = vfma(w, h[j],  z);
                    j0 = vfma(w, J0[j], j0);
                    j1 = vfma(w, J1[j], j1);
                }
                v2f hk, dk;
                act2(z, hk, dk);
                hn[k]  = hk;
                Jn0[k] = dk * j0;
                Jn1[k] = dk * j1;
            }
            #pragma unroll
            for (int k = 0; k < DH; ++k) { h[k] = hn[k]; J0[k] = Jn0[k]; J1[k] = Jn1[k]; }
        }

        // ---- output layer ----
        v2f y[2], dpv[2], o0[2], o1[2];
        #pragma unroll
        for (int r = 0; r < 2; ++r) {
            v2f z  = splat(wo[r][0]) * h[0];
            v2f j0 = splat(wo[r][0]) * J0[0];
            v2f j1 = splat(wo[r][0]) * J1[0];
            #pragma unroll
            for (int j = 1; j < DH; ++j) {
                v2f w = splat(wo[r][j]);
                z  = vfma(w, h[j],  z);
                j0 = vfma(w, J0[j], j0);
                j1 = vfma(w, J1[j], j1);
            }
            v2f yk, dk;
            act2(z, yk, dk);
            y[r] = yk; dpv[r] = dk;
            o0[r] = j0; o1[r] = j1;
        }

        // det = d0'*d1'*(o0[0]*o1[1] - o1[0]*o0[1])  (c^2 cancels exactly)
        v2f cross = vfma(-o1[0], o0[1], o0[0] * o1[1]);
        v2f det   = (dpv[0] * dpv[1]) * cross;
        v2f lg;
        lg.x = __builtin_amdgcn_logf(fabsf(det.x));
        lg.y = __builtin_amdgcn_logf(fabsf(det.y));
        rld[p] = vfma(splat(LN2), lg, plj[p]);
        ry0[p] = y[0];
        ry1[p] = y[1];
    }

    // ---- assemble 24 floats -> 6 float4 stores (pattern repeats per 2 pairs) ----
    #pragma unroll
    for (int g = 0; g < NPAIR/2; ++g) {
        int pa = 2*g, pb = 2*g + 1;
        out4[(size_t)t * 6 + 3*g + 0] =
            make_float4(ry0[pa].x, ry1[pa].x, rld[pa].x, ry0[pa].y);
        out4[(size_t)t * 6 + 3*g + 1] =
            make_float4(ry1[pa].y, rld[pa].y, ry0[pb].x, ry1[pb].x);
        out4[(size_t)t * 6 + 3*g + 2] =
            make_float4(rld[pb].x, ry0[pb].y, ry1[pb].y, rld[pb].y);
    }
}

extern "C" void kernel_launch(void* const* d_in, const int* in_sizes, int n_in,
                              void* d_out, int out_size, void* d_ws, size_t ws_size,
                              hipStream_t stream) {
    const float* xj   = (const float*)d_in[0];
    const float* W0   = (const float*)d_in[1];
    const float* Ws   = (const float*)d_in[2];
    const float* Wout = (const float*)d_in[3];
    float* out = (float*)d_out;
    float* wsf = (float*)d_ws;

    prescale_kernel<<<1, 128, 0, stream>>>(W0, Ws, Wout, wsf);

    int n = in_sizes[0] / (D + 1);   // 4194304
    int noct = n / 8;                // 524288 threads, 8 samples each

    dim3 block(256);
    dim3 grid((noct + block.x - 1) / block.x);
    nnflow_kernel<<<grid, block, 0, stream>>>(
        (const float4*)xj, wsf, (float4*)out, noct);
}

// Round 9
// 51.883 us; speedup vs baseline: 1.0805x; 1.0805x over previous
//
#include <hip/hip_runtime.h>
#include <hip/hip_fp16.h>

#define D 2
#define DH 5
#define NH 3
#define NW0 (DH*D)            // 10
#define NWS (NH*DH*DH)        // 75
#define NWTOT (NW0+NWS+D*DH)  // 95

// c = 2*log2(e): weights pre-scaled so exp2 needs no argument mul.
#define C_SCALE 2.8853900817779268f
#define K03C 0.10397207708399180f   // 0.3/c
#define K28C 0.97040605462392273f   // 2.8/c
#define LN2  0.69314718055994531f

// Packed f16 activation for a sample-pair: zp = c*z (both halves).
//   r = 1/(2^{zp}+1);  h = 0.3z+0.7-1.4r;  d' = 0.3/c + (2.8/c)(r-r^2)
// Saturation: exp2 -> inf/0 gives r -> 0/1, the exact asymptote.
__device__ __forceinline__ void act2h(__half2 zp, __half2& h, __half2& dp,
                                      __half2 one2, __half2 k03, __half2 k28,
                                      __half2 c07, __half2 n14) {
    __half2 e = h2exp2(zp);
    __half2 a = __hadd2(e, one2);
    __half2 r = h2rcp(a);
    __half2 u = __hfma2(__hneg2(r), r, r);            // r - r^2
    dp = __hfma2(k28, u, k03);
    h  = __hfma2(n14, r, __hfma2(k03, zp, c07));
}

// Pre-scale weights by c, convert to f16, and splat into both halves of a
// uint32 so the main kernel can keep them in SGPRs as VOP3P broadcast srcs.
__global__ void prescale_kernel(const float* __restrict__ gW0,
                                const float* __restrict__ gWs,
                                const float* __restrict__ gWout,
                                unsigned int* __restrict__ wsu) {
    int i = threadIdx.x;
    float w;
    if (i < NW0)            w = gW0[i];
    else if (i < NW0+NWS)   w = gWs[i - NW0];
    else if (i < NWTOT)     w = gWout[i - NW0 - NWS];
    else return;
    __half hw = __float2half_rn(C_SCALE * w);
    unsigned short us = __half_as_ushort(hw);
    wsu[i] = (unsigned int)us | ((unsigned int)us << 16);
}

__global__ __launch_bounds__(256) void nnflow_kernel(
    const float4* __restrict__ xj4,
    const unsigned int* __restrict__ wsu,
    float4* __restrict__ out4,
    int nquads)
{
    int t = blockIdx.x * blockDim.x + threadIdx.x;
    if (t >= nquads) return;

    // ---- splatted f16 weight pairs: uniform address + const idx -> SGPRs ----
    unsigned int wu[NWTOT];
    #pragma unroll
    for (int i = 0; i < NWTOT; ++i) wu[i] = wsu[i];
    #define W0H(k,j)   __builtin_bit_cast(__half2, wu[(k)*D+(j)])
    #define WSH(i,k,j) __builtin_bit_cast(__half2, wu[NW0 + ((i)*DH+(k))*DH+(j)])
    #define WOH(r,j)   __builtin_bit_cast(__half2, wu[NW0+NWS+(r)*DH+(j)])

    const __half2 one2 = __float2half2_rn(1.0f);
    const __half2 k03  = __float2half2_rn(K03C);
    const __half2 k28  = __float2half2_rn(K28C);
    const __half2 c07  = __float2half2_rn(0.7f);
    const __half2 n14  = __float2half2_rn(-1.4f);

    // ---- 4 samples = 12 floats = 3 float4, coalesced; 2 sample-pairs ----
    float4 v0 = xj4[(size_t)t * 3 + 0];
    float4 v1 = xj4[(size_t)t * 3 + 1];
    float4 v2 = xj4[(size_t)t * 3 + 2];

    __half2 px0[2], px1[2];
    float plj[2][2];
    px0[0] = __floats2half2_rn(v0.x, v0.w);  px0[1] = __floats2half2_rn(v1.z, v2.y);
    px1[0] = __floats2half2_rn(v0.y, v1.x);  px1[1] = __floats2half2_rn(v1.w, v2.z);
    plj[0][0] = v0.z; plj[0][1] = v1.y;      plj[1][0] = v2.x; plj[1][1] = v2.w;

    float ry0[2][2], ry1[2][2], rld[2][2];

    #pragma unroll
    for (int p = 0; p < 2; ++p) {
        __half2 x0 = px0[p], x1 = px1[p];

        // ---- layer 0 ----
        __half2 h[DH], J0[DH], J1[DH];
        #pragma unroll
        for (int k = 0; k < DH; ++k) {
            __half2 z = __hfma2(W0H(k,0), x0, __hmul2(W0H(k,1), x1));
            __half2 hk, dk;
            act2h(z, hk, dk, one2, k03, k28, c07, n14);
            h[k]  = hk;
            J0[k] = __hmul2(W0H(k,0), dk);
            J1[k] = __hmul2(W0H(k,1), dk);
        }

        // ---- hidden layers ----
        #pragma unroll
        for (int i = 0; i < NH; ++i) {
            __half2 hn[DH], Jn0[DH], Jn1[DH];
            #pragma unroll
            for (int k = 0; k < DH; ++k) {
                __half2 z  = __hmul2(WSH(i,k,0), h[0]);
                __half2 j0 = __hmul2(WSH(i,k,0), J0[0]);
                __half2 j1 = __hmul2(WSH(i,k,0), J1[0]);
                #pragma unroll
                for (int j = 1; j < DH; ++j) {
                    __half2 w = WSH(i,k,j);
                    z  = __hfma2(w, h[j],  z);
                    j0 = __hfma2(w, J0[j], j0);
                    j1 = __hfma2(w, J1[j], j1);
                }
                __half2 hk, dk;
                act2h(z, hk, dk, one2, k03, k28, c07, n14);
                hn[k]  = hk;
                Jn0[k] = __hmul2(dk, j0);
                Jn1[k] = __hmul2(dk, j1);
            }
            #pragma unroll
            for (int k = 0; k < DH; ++k) { h[k] = hn[k]; J0[k] = Jn0[k]; J1[k] = Jn1[k]; }
        }

        // ---- output layer ----
        __half2 y[2], dpv[2], o0[2], o1[2];
        #pragma unroll
        for (int r = 0; r < 2; ++r) {
            __half2 z  = __hmul2(WOH(r,0), h[0]);
            __half2 j0 = __hmul2(WOH(r,0), J0[0]);
            __half2 j1 = __hmul2(WOH(r,0), J1[0]);
            #pragma unroll
            for (int j = 1; j < DH; ++j) {
                __half2 w = WOH(r,j);
                z  = __hfma2(w, h[j],  z);
                j0 = __hfma2(w, J0[j], j0);
                j1 = __hfma2(w, J1[j], j1);
            }
            __half2 yk, dk;
            act2h(z, yk, dk, one2, k03, k28, c07, n14);
            y[r] = yk; dpv[r] = dk;
            o0[r] = j0; o1[r] = j1;
        }

        // ---- det + log in f32 (kills cancellation/subnormal risk) ----
        #pragma unroll
        for (int hx = 0; hx < 2; ++hx) {
            float a00 = (hx ? __high2float(o0[0]) : __low2float(o0[0]));
            float a01 = (hx ? __high2float(o1[0]) : __low2float(o1[0]));
            float a10 = (hx ? __high2float(o0[1]) : __low2float(o0[1]));
            float a11 = (hx ? __high2float(o1[1]) : __low2float(o1[1]));
            float d0  = (hx ? __high2float(dpv[0]) : __low2float(dpv[0]));
            float d1  = (hx ? __high2float(dpv[1]) : __low2float(dpv[1]));
            // det = d0'*d1'*(a00*a11 - a01*a10)  (c^2 cancels exactly)
            float cross = fmaf(-a01, a10, a00 * a11);
            float det   = (d0 * d1) * cross;
            float lg    = __builtin_amdgcn_logf(fabsf(det));
            rld[p][hx] = fmaf(LN2, lg, plj[p][hx]);
            ry0[p][hx] = (hx ? __high2float(y[0]) : __low2float(y[0]));
            ry1[p][hx] = (hx ? __high2float(y[1]) : __low2float(y[1]));
        }
    }

    // ---- assemble 12 floats -> 3 float4 stores ----
    out4[(size_t)t * 3 + 0] = make_float4(ry0[0][0], ry1[0][0], rld[0][0], ry0[0][1]);
    out4[(size_t)t * 3 + 1] = make_float4(ry1[0][1], rld[0][1], ry0[1][0], ry1[1][0]);
    out4[(size_t)t * 3 + 2] = make_float4(rld[1][0], ry0[1][1], ry1[1][1], rld[1][1]);
}

extern "C" void kernel_launch(void* const* d_in, const int* in_sizes, int n_in,
                              void* d_out, int out_size, void* d_ws, size_t ws_size,
                              hipStream_t stream) {
    const float* xj   = (const float*)d_in[0];
    const float* W0   = (const float*)d_in[1];
    const float* Ws   = (const float*)d_in[2];
    const float* Wout = (const float*)d_in[3];
    float* out = (float*)d_out;
    unsigned int* wsu = (unsigned int*)d_ws;

    prescale_kernel<<<1, 128, 0, stream>>>(W0, Ws, Wout, wsu);

    int n = in_sizes[0] / (D + 1);   // 4194304
    int nquads = n / 4;              // 4 samples per thread

    dim3 block(256);
    dim3 grid((nquads + block.x - 1) / block.x);
    nnflow_kernel<<<grid, block, 0, stream>>>(
        (const float4*)xj, wsu, (float4*)out, nquads);
}

// Round 10
// 51.273 us; speedup vs baseline: 1.0933x; 1.0119x over previous
//
#include <hip/hip_runtime.h>
#include <hip/hip_fp16.h>

#define D 2
#define DH 5
#define NH 3
#define NW0 (DH*D)            // 10
#define NWS (NH*DH*DH)        // 75
#define NWTOT (NW0+NWS+D*DH)  // 95

#define NP 2                  // sample-pairs per thread (4 samples)

// c = 2*log2(e): weights pre-scaled so exp2 needs no argument mul.
#define C_SCALE 2.8853900817779268f
#define K03C 0.10397207708399180f   // 0.3/c
#define K28C 0.97040605462392273f   // 2.8/c
#define LN2  0.69314718055994531f

// Packed f16 activation, both halves of a sample-pair.
__device__ __forceinline__ void act2h(__half2 zp, __half2& h, __half2& dp,
                                      __half2 one2, __half2 k03, __half2 k28,
                                      __half2 c07, __half2 n14) {
    __half2 e = h2exp2(zp);
    __half2 a = __hadd2(e, one2);
    __half2 r = h2rcp(a);
    __half2 u = __hfma2(__hneg2(r), r, r);            // r - r^2
    dp = __hfma2(k28, u, k03);
    h  = __hfma2(n14, r, __hfma2(k03, zp, c07));
}

// Pre-scale weights by c, convert to f16, splat into both halves of a uint32.
__global__ void prescale_kernel(const float* __restrict__ gW0,
                                const float* __restrict__ gWs,
                                const float* __restrict__ gWout,
                                unsigned int* __restrict__ wsu) {
    int i = threadIdx.x;
    float w;
    if (i < NW0)            w = gW0[i];
    else if (i < NW0+NWS)   w = gWs[i - NW0];
    else if (i < NWTOT)     w = gWout[i - NW0 - NWS];
    else return;
    __half hw = __float2half_rn(C_SCALE * w);
    unsigned short us = __half_as_ushort(hw);
    wsu[i] = (unsigned int)us | ((unsigned int)us << 16);
}

__global__ __launch_bounds__(256) void nnflow_kernel(
    const float4* __restrict__ xj4,
    const unsigned int* __restrict__ wsu,
    float4* __restrict__ out4,
    int nquads)
{
    int t = blockIdx.x * blockDim.x + threadIdx.x;
    if (t >= nquads) return;

    // ---- splatted f16 weight pairs (SGPRs) ----
    unsigned int wu[NWTOT];
    #pragma unroll
    for (int i = 0; i < NWTOT; ++i) wu[i] = wsu[i];
    #define W0H(k,j)   __builtin_bit_cast(__half2, wu[(k)*D+(j)])
    #define WSH(i,k,j) __builtin_bit_cast(__half2, wu[NW0 + ((i)*DH+(k))*DH+(j)])
    #define WOH(r,j)   __builtin_bit_cast(__half2, wu[NW0+NWS+(r)*DH+(j)])

    const __half2 one2 = __float2half2_rn(1.0f);
    const __half2 k03  = __float2half2_rn(K03C);
    const __half2 k28  = __float2half2_rn(K28C);
    const __half2 c07  = __float2half2_rn(0.7f);
    const __half2 n14  = __float2half2_rn(-1.4f);

    // ---- 4 samples = 3 float4, coalesced; 2 sample-pairs ----
    float4 v0 = xj4[(size_t)t * 3 + 0];
    float4 v1 = xj4[(size_t)t * 3 + 1];
    float4 v2 = xj4[(size_t)t * 3 + 2];

    __half2 px0[NP], px1[NP];
    float plj[NP][2];
    px0[0] = __floats2half2_rn(v0.x, v0.w);  px0[1] = __floats2half2_rn(v1.z, v2.y);
    px1[0] = __floats2half2_rn(v0.y, v1.x);  px1[1] = __floats2half2_rn(v1.w, v2.z);
    plj[0][0] = v0.z; plj[0][1] = v1.y;      plj[1][0] = v2.x; plj[1][1] = v2.w;

    // ---- LAYER-LOCKSTEP across pairs: adjacent independent chains ----
    __half2 h[NP][DH], J0[NP][DH], J1[NP][DH];

    // layer 0 (10 independent activation chains)
    #pragma unroll
    for (int p = 0; p < NP; ++p) {
        #pragma unroll
        for (int k = 0; k < DH; ++k) {
            __half2 z = __hfma2(W0H(k,0), px0[p], __hmul2(W0H(k,1), px1[p]));
            __half2 hk, dk;
            act2h(z, hk, dk, one2, k03, k28, c07, n14);
            h[p][k]  = hk;
            J0[p][k] = __hmul2(W0H(k,0), dk);
            J1[p][k] = __hmul2(W0H(k,1), dk);
        }
    }

    // hidden layers (per layer: 10 independent chains across pairs)
    #pragma unroll
    for (int i = 0; i < NH; ++i) {
        __half2 hn[NP][DH], Jn0[NP][DH], Jn1[NP][DH];
        #pragma unroll
        for (int p = 0; p < NP; ++p) {
            #pragma unroll
            for (int k = 0; k < DH; ++k) {
                __half2 z  = __hmul2(WSH(i,k,0), h[p][0]);
                __half2 j0 = __hmul2(WSH(i,k,0), J0[p][0]);
                __half2 j1 = __hmul2(WSH(i,k,0), J1[p][0]);
                #pragma unroll
                for (int j = 1; j < DH; ++j) {
                    __half2 w = WSH(i,k,j);
                    z  = __hfma2(w, h[p][j],  z);
                    j0 = __hfma2(w, J0[p][j], j0);
                    j1 = __hfma2(w, J1[p][j], j1);
                }
                __half2 hk, dk;
                act2h(z, hk, dk, one2, k03, k28, c07, n14);
                hn[p][k]  = hk;
                Jn0[p][k] = __hmul2(dk, j0);
                Jn1[p][k] = __hmul2(dk, j1);
            }
        }
        #pragma unroll
        for (int p = 0; p < NP; ++p)
            #pragma unroll
            for (int k = 0; k < DH; ++k) {
                h[p][k] = hn[p][k]; J0[p][k] = Jn0[p][k]; J1[p][k] = Jn1[p][k];
            }
    }

    // output layer (4 independent chains)
    __half2 y[NP][2], dpv[NP][2], o0[NP][2], o1[NP][2];
    #pragma unroll
    for (int p = 0; p < NP; ++p) {
        #pragma unroll
        for (int r = 0; r < 2; ++r) {
            __half2 z  = __hmul2(WOH(r,0), h[p][0]);
            __half2 j0 = __hmul2(WOH(r,0), J0[p][0]);
            __half2 j1 = __hmul2(WOH(r,0), J1[p][0]);
            #pragma unroll
            for (int j = 1; j < DH; ++j) {
                __half2 w = WOH(r,j);
                z  = __hfma2(w, h[p][j],  z);
                j0 = __hfma2(w, J0[p][j], j0);
                j1 = __hfma2(w, J1[p][j], j1);
            }
            __half2 yk, dk;
            act2h(z, yk, dk, one2, k03, k28, c07, n14);
            y[p][r] = yk; dpv[p][r] = dk;
            o0[p][r] = j0; o1[p][r] = j1;
        }
    }

    // det + log in f32 (4 independent chains)
    float ry0[NP][2], ry1[NP][2], rld[NP][2];
    #pragma unroll
    for (int p = 0; p < NP; ++p) {
        #pragma unroll
        for (int hx = 0; hx < 2; ++hx) {
            float a00 = (hx ? __high2float(o0[p][0]) : __low2float(o0[p][0]));
            float a01 = (hx ? __high2float(o1[p][0]) : __low2float(o1[p][0]));
            float a10 = (hx ? __high2float(o0[p][1]) : __low2float(o0[p][1]));
            float a11 = (hx ? __high2float(o1[p][1]) : __low2float(o1[p][1]));
            float d0  = (hx ? __high2float(dpv[p][0]) : __low2float(dpv[p][0]));
            float d1  = (hx ? __high2float(dpv[p][1]) : __low2float(dpv[p][1]));
            float cross = fmaf(-a01, a10, a00 * a11);
            float det   = (d0 * d1) * cross;
            float lg    = __builtin_amdgcn_logf(fabsf(det));
            rld[p][hx] = fmaf(LN2, lg, plj[p][hx]);
            ry0[p][hx] = (hx ? __high2float(y[p][0]) : __low2float(y[p][0]));
            ry1[p][hx] = (hx ? __high2float(y[p][1]) : __low2float(y[p][1]));
        }
    }

    // ---- assemble 12 floats -> 3 float4 stores ----
    out4[(size_t)t * 3 + 0] = make_float4(ry0[0][0], ry1[0][0], rld[0][0], ry0[0][1]);
    out4[(size_t)t * 3 + 1] = make_float4(ry1[0][1], rld[0][1], ry0[1][0], ry1[1][0]);
    out4[(size_t)t * 3 + 2] = make_float4(rld[1][0], ry0[1][1], ry1[1][1], rld[1][1]);
}

extern "C" void kernel_launch(void* const* d_in, const int* in_sizes, int n_in,
                              void* d_out, int out_size, void* d_ws, size_t ws_size,
                              hipStream_t stream) {
    const float* xj   = (const float*)d_in[0];
    const float* W0   = (const float*)d_in[1];
    const float* Ws   = (const float*)d_in[2];
    const float* Wout = (const float*)d_in[3];
    float* out = (float*)d_out;
    unsigned int* wsu = (unsigned int*)d_ws;

    prescale_kernel<<<1, 128, 0, stream>>>(W0, Ws, Wout, wsu);

    int n = in_sizes[0] / (D + 1);   // 4194304
    int nquads = n / 4;              // 4 samples per thread

    dim3 block(256);
    dim3 grid((nquads + block.x - 1) / block.x);
    nnflow_kernel<<<grid, block, 0, stream>>>(
        (const float4*)xj, wsu, (float4*)out, nquads);
}